// Round 11
// baseline (164.053 us; speedup 1.0000x reference)
//
#include <hip/hip_runtime.h>
#include <stdint.h>

typedef __bf16 bf16;
typedef __bf16 bf16x8 __attribute__((ext_vector_type(8)));
typedef float  f32x4  __attribute__((ext_vector_type(4)));

#if __has_builtin(__builtin_amdgcn_exp2f)
#define EXP2F(x) __builtin_amdgcn_exp2f(x)
#else
#define EXP2F(x) exp2f(x)
#endif

// LDS-only barrier: drain ds ops, leave vmcnt (global prefetch) in flight.
#define LGKM_BARRIER()                                    \
  do {                                                    \
    asm volatile("s_waitcnt lgkmcnt(0)" ::: "memory");    \
    __builtin_amdgcn_s_barrier();                         \
  } while (0)

constexpr int Bn = 8192, Sn = 256, Rn = 8192;
constexpr int BM = 64, BK = 32, KP = 4;
constexpr int KLEN = Rn / KP;   // 2048
constexpr int NC = KLEN / BK;   // 64 chunks per block
constexpr int PH = 64;          // k-width per barrier phase (2 chunks)
constexpr int NP = KLEN / PH;   // 32 phases

// ---------- prep: in-LDS type-sort + params/perb + inc->bf16 tiled + abund transpose ----------
// Blocks 0..255: per-row inc convert (+ sort, params, perb as before).
// Blocks 256..767: 64x64 transpose tiles abund[b][s] -> abT[s][b] (f32).
// Blocks 768..799: abT ones row (s = Sn).
__global__ __launch_bounds__(256) void prep_all(
    const float* __restrict__ inc, bf16* __restrict__ incb,
    const float* __restrict__ alpha, const float* __restrict__ beta,
    const float* __restrict__ gam, const int* __restrict__ rm, const int* __restrict__ rtype,
    float4* __restrict__ params, const float* __restrict__ temp,
    const float* __restrict__ cr, const float* __restrict__ fuv, float4* __restrict__ perb,
    const float* __restrict__ abund, float* __restrict__ abT) {
  __shared__ __align__(16) float row_lds[8192];   // 32 KB (rtype ints / inc floats / transpose tile)
  __shared__ unsigned short perm_lds[8192];       // 16 KB
  __shared__ int c0[256], c1[256], c2[256];
  const int g = blockIdx.x, t = threadIdx.x;

  if (g >= 768) {  // ones row of abT
    abT[(size_t)Sn * Bn + (size_t)(g - 768) * 256 + t] = 1.0f;
    return;
  }
  if (g >= 256) {  // transpose tile: abund[bi*64..+64][sj*64..+64] -> abT
    const int gg = g - 256;
    const int bi = gg >> 2, sj = gg & 3;
    float (*tile)[65] = (float(*)[65])row_lds;   // 64x65 f32 = 16.6 KB
    const int r0 = t >> 4, c4 = (t & 15) * 4;
#pragma unroll
    for (int i = 0; i < 4; ++i) {
      int r = r0 + i * 16;
      float4 v = *(const float4*)(abund + (size_t)(bi * 64 + r) * Sn + sj * 64 + c4);
      tile[r][c4 + 0] = v.x; tile[r][c4 + 1] = v.y;
      tile[r][c4 + 2] = v.z; tile[r][c4 + 3] = v.w;
    }
    __syncthreads();
#pragma unroll
    for (int i = 0; i < 4; ++i) {
      int s = r0 + i * 16;
      float4 o = make_float4(tile[c4 + 0][s], tile[c4 + 1][s],
                             tile[c4 + 2][s], tile[c4 + 3][s]);
      *(float4*)(abT + (size_t)(sj * 64 + s) * Bn + bi * 64 + c4) = o;
    }
    return;
  }

  // 1) stage rtype -> LDS (coalesced int4)
  int* rt = (int*)row_lds;
  {
    const int4* src = (const int4*)rtype;
    int4* dst = (int4*)rt;
#pragma unroll
    for (int i = 0; i < 8; ++i) dst[i * 256 + t] = src[i * 256 + t];
  }
  __syncthreads();

  // 2) count (thread t owns r = i*256+t), scan, write perm
  int ty[32];
  int l0 = 0, l1 = 0, l2 = 0;
#pragma unroll
  for (int i = 0; i < 32; ++i) {
    int v = rt[i * 256 + t];
    ty[i] = v;
    l0 += (v == 0); l1 += (v == 1); l2 += (v == 2);
  }
  c0[t] = l0; c1[t] = l1; c2[t] = l2;
  __syncthreads();
  for (int off = 1; off < 256; off <<= 1) {
    int a = (t >= off) ? c0[t - off] : 0;
    int b = (t >= off) ? c1[t - off] : 0;
    int c = (t >= off) ? c2[t - off] : 0;
    __syncthreads();
    c0[t] += a; c1[t] += b; c2[t] += c;
    __syncthreads();
  }
  const int tot0 = c0[255], tot1 = c1[255];
  int o0 = c0[t] - l0;                  // exclusive offsets per bucket
  int o1 = tot0 + c1[t] - l1;
  int o2 = tot0 + tot1 + c2[t] - l2;
#pragma unroll
  for (int i = 0; i < 32; ++i) {
    int v = ty[i];
    int pos = (v == 0) ? o0++ : ((v == 1) ? o1++ : o2++);
    perm_lds[pos] = (unsigned short)(i * 256 + t);
  }
  __syncthreads();

  // 3) params / perb (rt[] still valid; perm_lds ready)
  if (g < 32) {
    int p = g * 256 + t;
    int r = perm_lds[p];
    float a = alpha[r], be = beta[r], gm = gam[r];
    int tv = rt[r];
    int i0 = rm[2 * r], i1 = rm[2 * r + 1];
    float x, P = 0.0f, Q = 0.0f;
    if (tv == 0) { x = __log2f(a); P = be; Q = gm; }       // exp2(x + P*l2t - Q*itv)
    else if (tv == 1) { x = a; }                            // x * cr
    else { x = a * expf(-gm); }                             // x * fuv
    uint32_t bits = (uint32_t)i0 | ((uint32_t)i1 << 10) | ((uint32_t)tv << 20);
    params[p] = make_float4(x, P, Q, __uint_as_float(bits));
  } else if (g < 64) {
    int b = (g - 32) * 256 + t;
    float T = temp[b];
    perb[b] = make_float4(__log2f(T * (1.0f / 300.0f)), 1.4426950408889634f / T,
                          cr[b], fuv[b]);
  }
  __syncthreads();

  // 4) stage inc row g (32 KB, coalesced)
  {
    const float4* src = (const float4*)(inc + ((size_t)g << 13));
    float4* dst = (float4*)row_lds;
#pragma unroll
    for (int i = 0; i < 8; ++i) dst[i * 256 + t] = src[i * 256 + t];
  }
  __syncthreads();

  // 5) gather permuted columns -> incb[kt=t][row=g][32]
  const unsigned short* pp = perm_lds + t * 32;
  bf16* outp = incb + ((size_t)t * 256 + g) * 32;
#pragma unroll
  for (int k8 = 0; k8 < 4; ++k8) {
    bf16x8 o;
#pragma unroll
    for (int i = 0; i < 8; ++i) o[i] = (bf16)row_lds[pp[k8 * 8 + i]];
    *(bf16x8*)(outp + k8 * 8) = o;
  }
}

// ---------- fused flux + GEMM: VMEM abundance gathers (abT), flux-only LDS ----------
__global__ __launch_bounds__(256, 2) void flux_gemm(
    const float* __restrict__ abT, const float4* __restrict__ perb,
    const float4* __restrict__ params, const bf16* __restrict__ incb,
    float* __restrict__ partial) {
  __shared__ bf16 flux_lds[2][64 * PH];    // 16,384 B: [m][k64], octets XOR(row&7)-swizzled

  const int tid  = threadIdx.x;
  const int lane = tid & 63;
  const int w    = tid >> 6;
  const int ws   = __builtin_amdgcn_readfirstlane(w);  // provably-uniform warp id
  // XCD-aware: consecutive blockIdx round-robins XCDs; same-XCD blocks share kp
  const int x   = blockIdx.x & 7;
  const int jb  = blockIdx.x >> 3;         // 0..63
  const int kp  = x & 3;
  const int m0g = (jb * 2 + (x >> 2)) * BM;
  const int kstart = kp * KLEN;
  const int r16 = lane & 15, q = lane >> 4;

  // per-lane abundance-gather base: column b = m0g + lane of abT (row stride Bn)
  const float* abTb = abT + m0g + lane;

  // params for phase ph, this warp: pr[sub*8+j] = params[kstart + ph*64 + sub*32 + ws*8 + j]
  auto load_params = [&](int ph, float4* pr) {
    const float4* pw = params + kstart + ph * PH + ws * 8;
#pragma unroll
    for (int j = 0; j < 8; ++j) pr[j] = pw[j];
#pragma unroll
    for (int j = 0; j < 8; ++j) pr[8 + j] = pw[32 + j];
  };

  float4 prbuf[16];
  load_params(0, prbuf);   // issued early: covered by perb load below

  float4 pb = perb[m0g + lane];
  const float l2t = pb.x, nitv = -pb.y, crv = pb.z, fuvv = pb.w;

  // flux phase tile: issue ALL 32 gathers first (coalesced 256B VMEM loads via
  // wave-uniform row index), then compute per 8-octet sub with type-pure branch.
  // Write: row=lane, logical octet L = sub*4+ws stored at phys = L ^ (lane&7).
  auto flux_tile = [&](int buf, const float4* pr) {
    float a0v[16], a1v[16];
#pragma unroll
    for (int j = 0; j < 16; ++j) {
      uint32_t bits = __builtin_amdgcn_readfirstlane(__float_as_uint(pr[j].w));
      int i0 = (int)(bits & 1023), i1 = (int)((bits >> 10) & 1023);
      a0v[j] = abTb[(size_t)i0 * Bn];
      a1v[j] = abTb[(size_t)i1 * Bn];
    }
#pragma unroll
    for (int sub = 0; sub < 2; ++sub) {
      const float4* prs = pr + sub * 8;
      const float* A0 = a0v + sub * 8;
      const float* A1 = a1v + sub * 8;
      uint32_t b0 = __builtin_amdgcn_readfirstlane(__float_as_uint(prs[0].w));
      uint32_t b7 = __builtin_amdgcn_readfirstlane(__float_as_uint(prs[7].w));
      uint32_t t0 = b0 >> 20, t7 = b7 >> 20;
      bf16x8 fv;
      if (t0 == 0 && t7 == 0) {
#pragma unroll
        for (int j = 0; j < 8; ++j) {
          float v = EXP2F(fmaf(prs[j].y, l2t, fmaf(prs[j].z, nitv, prs[j].x)));
          fv[j] = (bf16)(v * (A0[j] * A1[j]));
        }
      } else if (t0 == t7) {
        float mv = (t0 == 1) ? crv : fuvv;
#pragma unroll
        for (int j = 0; j < 8; ++j)
          fv[j] = (bf16)((prs[j].x * mv) * (A0[j] * A1[j]));
      } else {
#pragma unroll
        for (int j = 0; j < 8; ++j) {
          uint32_t bits = __builtin_amdgcn_readfirstlane(__float_as_uint(prs[j].w));
          int ms = (int)(bits >> 20);
          float ve = EXP2F(fmaf(prs[j].y, l2t, fmaf(prs[j].z, nitv, prs[j].x)));
          float vm = prs[j].x * ((ms == 1) ? crv : fuvv);
          float v = (ms == 0) ? ve : vm;
          fv[j] = (bf16)(v * (A0[j] * A1[j]));
        }
      }
      *(bf16x8*)(flux_lds[buf] + lane * PH + (((sub * 4 + ws) ^ (lane & 7)) << 3)) = fv;
    }
  };

  // per-lane B base in tiled incb: chunk tile at chunk*8192; lane reads row
  // (w*64 + nt*16 + r16), 16B at col q*8 -> 1KB coalesced per frag.
  const bf16* bbase = incb + (size_t)(kstart / BK) * 8192 + (w * 64 + r16) * BK + q * 8;
  auto load_bfr = [&](int chunk, bf16x8* bfr) {
    const bf16* bp = bbase + (size_t)chunk * 8192;
#pragma unroll
    for (int nt = 0; nt < 4; ++nt)
      bfr[nt] = *(const bf16x8*)(bp + nt * (16 * BK));
  };

  flux_tile(0, prbuf);       // flux phase 0 -> flux_lds[0] (no ab staging needed)

  f32x4 acc[4][4];
#pragma unroll
  for (int i = 0; i < 4; ++i)
#pragma unroll
    for (int j = 0; j < 4; ++j) acc[i][j] = (f32x4)0.0f;

  for (int ph = 0; ph < NP; ++ph) {
    const int cur = ph & 1, nxt = cur ^ 1;
    LGKM_BARRIER();                          // flux_lds[cur] ready; vmcnt stays in flight

    // B-frags for both chunks of this phase (VMEM; covered by af+flux below)
    bf16x8 bfr[2][4];
    load_bfr(ph * 2, bfr[0]);
    load_bfr(ph * 2 + 1, bfr[1]);

    // A-frags: 8 independent b128 reads, row-XOR unswizzle
    bf16x8 af[2][4];
#pragma unroll
    for (int ks = 0; ks < 2; ++ks)
#pragma unroll
      for (int mt = 0; mt < 4; ++mt) {
        int row = mt * 16 + r16;
        af[ks][mt] = *(const bf16x8*)(flux_lds[cur] + row * PH +
                                      ((((ks << 2) + q) ^ (row & 7)) << 3));
      }

    if (ph + 1 < NP) {
      load_params(ph + 1, prbuf);
      flux_tile(nxt, prbuf);
    }

    __builtin_amdgcn_s_setprio(1);
#pragma unroll
    for (int ks = 0; ks < 2; ++ks)
#pragma unroll
      for (int mt = 0; mt < 4; ++mt)
#pragma unroll
        for (int nt = 0; nt < 4; ++nt)
          acc[mt][nt] = __builtin_amdgcn_mfma_f32_16x16x32_bf16(af[ks][mt], bfr[ks][nt],
                                                                acc[mt][nt], 0, 0, 0);
    __builtin_amdgcn_s_setprio(0);
  }

  // epilogue: plain stores of the split-K partial
  float* pout = partial + (size_t)kp * Bn * Sn;
#pragma unroll
  for (int mt = 0; mt < 4; ++mt)
#pragma unroll
    for (int nt = 0; nt < 4; ++nt) {
      int col = w * 64 + nt * 16 + r16;
      int row = m0g + mt * 16 + q * 4;
#pragma unroll
      for (int rg = 0; rg < 4; ++rg)
        pout[(size_t)(row + rg) * Sn + col] = acc[mt][nt][rg];
    }
}

// ---------- split-K reduce ----------
__global__ __launch_bounds__(256) void reduce_k(const float* __restrict__ partial,
                                               float* __restrict__ out) {
  size_t i = ((size_t)blockIdx.x * 256 + threadIdx.x) * 4;
  constexpr size_t NS = (size_t)Bn * Sn;
  float4 a = *(const float4*)(partial + i);
  float4 b = *(const float4*)(partial + NS + i);
  float4 c = *(const float4*)(partial + 2 * NS + i);
  float4 d = *(const float4*)(partial + 3 * NS + i);
  float4 r;
  r.x = (a.x + b.x) + (c.x + d.x);
  r.y = (a.y + b.y) + (c.y + d.y);
  r.z = (a.z + b.z) + (c.z + d.z);
  r.w = (a.w + b.w) + (c.w + d.w);
  *(float4*)(out + i) = r;
}

// ---------- launch: 3 kernels ----------
extern "C" void kernel_launch(void* const* d_in, const int* in_sizes, int n_in,
                              void* d_out, int out_size, void* d_ws, size_t ws_size,
                              hipStream_t stream) {
  const float* abund = (const float*)d_in[1];
  const float* temp  = (const float*)d_in[2];
  const float* cr    = (const float*)d_in[3];
  const float* fuv   = (const float*)d_in[4];
  const float* inc   = (const float*)d_in[5];
  const float* alpha = (const float*)d_in[6];
  const float* beta  = (const float*)d_in[7];
  const float* gam   = (const float*)d_in[8];
  const int*   rm    = (const int*)d_in[9];
  const int*   rty   = (const int*)d_in[10];
  float* out = (float*)d_out;

  // ws: params f4[8192] | perb f4[8192] | incb bf16[2M] | abT f32[(Sn+1)*Bn] | partial f32[4*2M]
  float4* params  = (float4*)d_ws;
  float4* perb    = params + Rn;
  bf16*   incb    = (bf16*)(perb + Bn);
  float*  abT     = (float*)(incb + (size_t)Sn * Rn);
  float*  partial = abT + (size_t)(Sn + 1) * Bn;

  prep_all<<<800, 256, 0, stream>>>(inc, incb, alpha, beta, gam, rm, rty,
                                    params, temp, cr, fuv, perb, abund, abT);
  flux_gemm<<<(Bn / BM) * KP, 256, 0, stream>>>(abT, perb, params, incb, partial);
  reduce_k<<<(Bn * Sn) / 1024, 256, 0, stream>>>(partial, out);
}

// Round 12
// 150.288 us; speedup vs baseline: 1.0916x; 1.0916x over previous
//
#include <hip/hip_runtime.h>
#include <stdint.h>

typedef __bf16 bf16;
typedef __bf16 bf16x8 __attribute__((ext_vector_type(8)));
typedef float  f32x4  __attribute__((ext_vector_type(4)));

#if __has_builtin(__builtin_amdgcn_exp2f)
#define EXP2F(x) __builtin_amdgcn_exp2f(x)
#else
#define EXP2F(x) exp2f(x)
#endif

// LDS-only barrier: drain ds ops, leave vmcnt (global prefetch) in flight.
#define LGKM_BARRIER()                                    \
  do {                                                    \
    asm volatile("s_waitcnt lgkmcnt(0)" ::: "memory");    \
    __builtin_amdgcn_s_barrier();                         \
  } while (0)

constexpr int Bn = 8192, Sn = 256, Rn = 8192;
constexpr int BM = 64, BK = 32, KP = 4;
constexpr int KLEN = Rn / KP;   // 2048
constexpr int NC = KLEN / BK;   // 64 chunks per block
constexpr int PH = 64;          // k-width per barrier phase (2 chunks)
constexpr int NP = KLEN / PH;   // 32 phases

// ---------- prep: in-LDS type-sort + params/perb + inc->bf16 tiled + abund transpose ----------
// Blocks 0..255: per-row inc convert (+ sort, params, perb).
// Blocks 256..767: 64x64 transpose tiles abund[b][s] -> abT[s][b] (f32).
// Blocks 768..799: abT ones row (s = Sn).
__global__ __launch_bounds__(256) void prep_all(
    const float* __restrict__ inc, bf16* __restrict__ incb,
    const float* __restrict__ alpha, const float* __restrict__ beta,
    const float* __restrict__ gam, const int* __restrict__ rm, const int* __restrict__ rtype,
    float4* __restrict__ params, const float* __restrict__ temp,
    const float* __restrict__ cr, const float* __restrict__ fuv, float4* __restrict__ perb,
    const float* __restrict__ abund, float* __restrict__ abT) {
  __shared__ __align__(16) float row_lds[8192];   // 32 KB (rtype ints / inc floats / transpose tile)
  __shared__ unsigned short perm_lds[8192];       // 16 KB
  __shared__ int c0[256], c1[256], c2[256];
  const int g = blockIdx.x, t = threadIdx.x;

  if (g >= 768) {  // ones row of abT
    abT[(size_t)Sn * Bn + (size_t)(g - 768) * 256 + t] = 1.0f;
    return;
  }
  if (g >= 256) {  // transpose tile: abund[bi*64..+64][sj*64..+64] -> abT
    const int gg = g - 256;
    const int bi = gg >> 2, sj = gg & 3;
    float (*tile)[65] = (float(*)[65])row_lds;   // 64x65 f32 = 16.6 KB
    const int r0 = t >> 4, c4 = (t & 15) * 4;
#pragma unroll
    for (int i = 0; i < 4; ++i) {
      int r = r0 + i * 16;
      float4 v = *(const float4*)(abund + (size_t)(bi * 64 + r) * Sn + sj * 64 + c4);
      tile[r][c4 + 0] = v.x; tile[r][c4 + 1] = v.y;
      tile[r][c4 + 2] = v.z; tile[r][c4 + 3] = v.w;
    }
    __syncthreads();
#pragma unroll
    for (int i = 0; i < 4; ++i) {
      int s = r0 + i * 16;
      float4 o = make_float4(tile[c4 + 0][s], tile[c4 + 1][s],
                             tile[c4 + 2][s], tile[c4 + 3][s]);
      *(float4*)(abT + (size_t)(sj * 64 + s) * Bn + bi * 64 + c4) = o;
    }
    return;
  }

  // 1) stage rtype -> LDS (coalesced int4)
  int* rt = (int*)row_lds;
  {
    const int4* src = (const int4*)rtype;
    int4* dst = (int4*)rt;
#pragma unroll
    for (int i = 0; i < 8; ++i) dst[i * 256 + t] = src[i * 256 + t];
  }
  __syncthreads();

  // 2) count (thread t owns r = i*256+t), scan, write perm
  int ty[32];
  int l0 = 0, l1 = 0, l2 = 0;
#pragma unroll
  for (int i = 0; i < 32; ++i) {
    int v = rt[i * 256 + t];
    ty[i] = v;
    l0 += (v == 0); l1 += (v == 1); l2 += (v == 2);
  }
  c0[t] = l0; c1[t] = l1; c2[t] = l2;
  __syncthreads();
  for (int off = 1; off < 256; off <<= 1) {
    int a = (t >= off) ? c0[t - off] : 0;
    int b = (t >= off) ? c1[t - off] : 0;
    int c = (t >= off) ? c2[t - off] : 0;
    __syncthreads();
    c0[t] += a; c1[t] += b; c2[t] += c;
    __syncthreads();
  }
  const int tot0 = c0[255], tot1 = c1[255];
  int o0 = c0[t] - l0;                  // exclusive offsets per bucket
  int o1 = tot0 + c1[t] - l1;
  int o2 = tot0 + tot1 + c2[t] - l2;
#pragma unroll
  for (int i = 0; i < 32; ++i) {
    int v = ty[i];
    int pos = (v == 0) ? o0++ : ((v == 1) ? o1++ : o2++);
    perm_lds[pos] = (unsigned short)(i * 256 + t);
  }
  __syncthreads();

  // 3) params / perb (rt[] still valid; perm_lds ready)
  if (g < 32) {
    int p = g * 256 + t;
    int r = perm_lds[p];
    float a = alpha[r], be = beta[r], gm = gam[r];
    int tv = rt[r];
    int i0 = rm[2 * r], i1 = rm[2 * r + 1];
    float x, P = 0.0f, Q = 0.0f;
    if (tv == 0) { x = __log2f(a); P = be; Q = gm; }       // exp2(x + P*l2t - Q*itv)
    else if (tv == 1) { x = a; }                            // x * cr
    else { x = a * expf(-gm); }                             // x * fuv
    uint32_t bits = (uint32_t)i0 | ((uint32_t)i1 << 10) | ((uint32_t)tv << 20);
    params[p] = make_float4(x, P, Q, __uint_as_float(bits));
  } else if (g < 64) {
    int b = (g - 32) * 256 + t;
    float T = temp[b];
    perb[b] = make_float4(__log2f(T * (1.0f / 300.0f)), 1.4426950408889634f / T,
                          cr[b], fuv[b]);
  }
  __syncthreads();

  // 4) stage inc row g (32 KB, coalesced)
  {
    const float4* src = (const float4*)(inc + ((size_t)g << 13));
    float4* dst = (float4*)row_lds;
#pragma unroll
    for (int i = 0; i < 8; ++i) dst[i * 256 + t] = src[i * 256 + t];
  }
  __syncthreads();

  // 5) gather permuted columns -> incb[kt=t][row=g][32]
  const unsigned short* pp = perm_lds + t * 32;
  bf16* outp = incb + ((size_t)t * 256 + g) * 32;
#pragma unroll
  for (int k8 = 0; k8 < 4; ++k8) {
    bf16x8 o;
#pragma unroll
    for (int i = 0; i < 8; ++i) o[i] = (bf16)row_lds[pp[k8 * 8 + i]];
    *(bf16x8*)(outp + k8 * 8) = o;
  }
}

// ---------- fused flux + GEMM: HYBRID gathers (a0 LDS, a1 VMEM) ----------
__global__ __launch_bounds__(256, 2) void flux_gemm(
    const float* __restrict__ abT, const float* __restrict__ abund,
    const float4* __restrict__ perb, const float4* __restrict__ params,
    const bf16* __restrict__ incb, float* __restrict__ partial) {
  __shared__ bf16 ab_lds[257 * 64];        // 32,896 B: [s][b] bf16 (a0 gathers)
  __shared__ bf16 flux_lds[2][64 * PH];    // 16,384 B: [m][k64], octets XOR(row&7)-swizzled

  const int tid  = threadIdx.x;
  const int lane = tid & 63;
  const int w    = tid >> 6;
  const int ws   = __builtin_amdgcn_readfirstlane(w);  // provably-uniform warp id
  // XCD-aware: consecutive blockIdx round-robins XCDs; same-XCD blocks share kp
  const int x   = blockIdx.x & 7;
  const int jb  = blockIdx.x >> 3;         // 0..63
  const int kp  = x & 3;
  const int m0g = (jb * 2 + (x >> 2)) * BM;
  const int kstart = kp * KLEN;
  const int r16 = lane & 15, q = lane >> 4;

  // per-lane a1-gather base: column b = m0g + lane of abT (row stride Bn)
  const float* abTb = abT + m0g + lane;

  // params for phase ph, this warp: pr[sub*8+j] = params[kstart + ph*64 + sub*32 + ws*8 + j]
  auto load_params = [&](int ph, float4* pr) {
    const float4* pw = params + kstart + ph * PH + ws * 8;
#pragma unroll
    for (int j = 0; j < 8; ++j) pr[j] = pw[j];
#pragma unroll
    for (int j = 0; j < 8; ++j) pr[8 + j] = pw[32 + j];
  };

  float4 prbuf[16];
  load_params(0, prbuf);   // issued early: covered by ab staging below

  // stage abundances tile transposed [s][b] bf16 (once per block; a0 source)
  {
    int bsub = tid >> 2;
    int scol = (tid & 3) * 64;
    const float* rowp = abund + (size_t)(m0g + bsub) * Sn + scol;
#pragma unroll
    for (int j = 0; j < 16; ++j) {
      float4 v = *(const float4*)(rowp + j * 4);
      int s = scol + j * 4;
      ab_lds[(s + 0) * 64 + bsub] = (bf16)v.x;
      ab_lds[(s + 1) * 64 + bsub] = (bf16)v.y;
      ab_lds[(s + 2) * 64 + bsub] = (bf16)v.z;
      ab_lds[(s + 3) * 64 + bsub] = (bf16)v.w;
    }
    if (tid < 64) ab_lds[256 * 64 + tid] = (bf16)1.0f;  // ones row (species index S)
  }

  float4 pb = perb[m0g + lane];
  const float l2t = pb.x, nitv = -pb.y, crv = pb.z, fuvv = pb.w;

  // flux phase tile: a1 via 16 coalesced VMEM loads (issued first, L2 latency hidden
  // under the a0 LDS gathers + VALU), a0 via 16 LDS u16 gathers. Splits the gather
  // load across the two memory pipes (r10 = all-LDS saturated LDS; r11 = all-VMEM
  // saturated L2). Write: row=lane, logical octet L = sub*4+ws at phys L^(lane&7).
  auto flux_tile = [&](int buf, const float4* pr) {
    float a1v[16];
#pragma unroll
    for (int j = 0; j < 16; ++j) {
      uint32_t bits = __builtin_amdgcn_readfirstlane(__float_as_uint(pr[j].w));
      int i1 = (int)((bits >> 10) & 1023);
      a1v[j] = abTb[(size_t)i1 * Bn];
    }
    float a0v[16];
#pragma unroll
    for (int j = 0; j < 16; ++j) {
      uint32_t bits = __builtin_amdgcn_readfirstlane(__float_as_uint(pr[j].w));
      int i0 = (int)(bits & 1023);
      a0v[j] = (float)ab_lds[i0 * 64 + lane];
    }
#pragma unroll
    for (int sub = 0; sub < 2; ++sub) {
      const float4* prs = pr + sub * 8;
      const float* A0 = a0v + sub * 8;
      const float* A1 = a1v + sub * 8;
      uint32_t b0 = __builtin_amdgcn_readfirstlane(__float_as_uint(prs[0].w));
      uint32_t b7 = __builtin_amdgcn_readfirstlane(__float_as_uint(prs[7].w));
      uint32_t t0 = b0 >> 20, t7 = b7 >> 20;
      bf16x8 fv;
      if (t0 == 0 && t7 == 0) {
#pragma unroll
        for (int j = 0; j < 8; ++j) {
          float v = EXP2F(fmaf(prs[j].y, l2t, fmaf(prs[j].z, nitv, prs[j].x)));
          fv[j] = (bf16)(v * (A0[j] * A1[j]));
        }
      } else if (t0 == t7) {
        float mv = (t0 == 1) ? crv : fuvv;
#pragma unroll
        for (int j = 0; j < 8; ++j)
          fv[j] = (bf16)((prs[j].x * mv) * (A0[j] * A1[j]));
      } else {
#pragma unroll
        for (int j = 0; j < 8; ++j) {
          uint32_t bits = __builtin_amdgcn_readfirstlane(__float_as_uint(prs[j].w));
          int ms = (int)(bits >> 20);
          float ve = EXP2F(fmaf(prs[j].y, l2t, fmaf(prs[j].z, nitv, prs[j].x)));
          float vm = prs[j].x * ((ms == 1) ? crv : fuvv);
          float v = (ms == 0) ? ve : vm;
          fv[j] = (bf16)(v * (A0[j] * A1[j]));
        }
      }
      *(bf16x8*)(flux_lds[buf] + lane * PH + (((sub * 4 + ws) ^ (lane & 7)) << 3)) = fv;
    }
  };

  // per-lane B base in tiled incb: chunk tile at chunk*8192; lane reads row
  // (w*64 + nt*16 + r16), 16B at col q*8 -> 1KB coalesced per frag.
  const bf16* bbase = incb + (size_t)(kstart / BK) * 8192 + (w * 64 + r16) * BK + q * 8;
  auto load_bfr = [&](int chunk, bf16x8* bfr) {
    const bf16* bp = bbase + (size_t)chunk * 8192;
#pragma unroll
    for (int nt = 0; nt < 4; ++nt)
      bfr[nt] = *(const bf16x8*)(bp + nt * (16 * BK));
  };

  __syncthreads();  // ab_lds ready (full barrier once; never written again)

  flux_tile(0, prbuf);       // flux phase 0 -> flux_lds[0]

  f32x4 acc[4][4];
#pragma unroll
  for (int i = 0; i < 4; ++i)
#pragma unroll
    for (int j = 0; j < 4; ++j) acc[i][j] = (f32x4)0.0f;

  for (int ph = 0; ph < NP; ++ph) {
    const int cur = ph & 1, nxt = cur ^ 1;
    LGKM_BARRIER();                          // flux_lds[cur] ready; vmcnt stays in flight

    // B-frags for both chunks of this phase (VMEM; covered by af+flux below)
    bf16x8 bfr[2][4];
    load_bfr(ph * 2, bfr[0]);
    load_bfr(ph * 2 + 1, bfr[1]);

    // A-frags: 8 independent b128 reads, row-XOR unswizzle
    bf16x8 af[2][4];
#pragma unroll
    for (int ks = 0; ks < 2; ++ks)
#pragma unroll
      for (int mt = 0; mt < 4; ++mt) {
        int row = mt * 16 + r16;
        af[ks][mt] = *(const bf16x8*)(flux_lds[cur] + row * PH +
                                      ((((ks << 2) + q) ^ (row & 7)) << 3));
      }

    if (ph + 1 < NP) {
      load_params(ph + 1, prbuf);
      flux_tile(nxt, prbuf);
    }

    __builtin_amdgcn_s_setprio(1);
#pragma unroll
    for (int ks = 0; ks < 2; ++ks)
#pragma unroll
      for (int mt = 0; mt < 4; ++mt)
#pragma unroll
        for (int nt = 0; nt < 4; ++nt)
          acc[mt][nt] = __builtin_amdgcn_mfma_f32_16x16x32_bf16(af[ks][mt], bfr[ks][nt],
                                                                acc[mt][nt], 0, 0, 0);
    __builtin_amdgcn_s_setprio(0);
  }

  // epilogue: plain stores of the split-K partial
  float* pout = partial + (size_t)kp * Bn * Sn;
#pragma unroll
  for (int mt = 0; mt < 4; ++mt)
#pragma unroll
    for (int nt = 0; nt < 4; ++nt) {
      int col = w * 64 + nt * 16 + r16;
      int row = m0g + mt * 16 + q * 4;
#pragma unroll
      for (int rg = 0; rg < 4; ++rg)
        pout[(size_t)(row + rg) * Sn + col] = acc[mt][nt][rg];
    }
}

// ---------- split-K reduce ----------
__global__ __launch_bounds__(256) void reduce_k(const float* __restrict__ partial,
                                               float* __restrict__ out) {
  size_t i = ((size_t)blockIdx.x * 256 + threadIdx.x) * 4;
  constexpr size_t NS = (size_t)Bn * Sn;
  float4 a = *(const float4*)(partial + i);
  float4 b = *(const float4*)(partial + NS + i);
  float4 c = *(const float4*)(partial + 2 * NS + i);
  float4 d = *(const float4*)(partial + 3 * NS + i);
  float4 r;
  r.x = (a.x + b.x) + (c.x + d.x);
  r.y = (a.y + b.y) + (c.y + d.y);
  r.z = (a.z + b.z) + (c.z + d.z);
  r.w = (a.w + b.w) + (c.w + d.w);
  *(float4*)(out + i) = r;
}

// ---------- launch: 3 kernels ----------
extern "C" void kernel_launch(void* const* d_in, const int* in_sizes, int n_in,
                              void* d_out, int out_size, void* d_ws, size_t ws_size,
                              hipStream_t stream) {
  const float* abund = (const float*)d_in[1];
  const float* temp  = (const float*)d_in[2];
  const float* cr    = (const float*)d_in[3];
  const float* fuv   = (const float*)d_in[4];
  const float* inc   = (const float*)d_in[5];
  const float* alpha = (const float*)d_in[6];
  const float* beta  = (const float*)d_in[7];
  const float* gam   = (const float*)d_in[8];
  const int*   rm    = (const int*)d_in[9];
  const int*   rty   = (const int*)d_in[10];
  float* out = (float*)d_out;

  // ws: params f4[8192] | perb f4[8192] | incb bf16[2M] | abT f32[(Sn+1)*Bn] | partial f32[4*2M]
  float4* params  = (float4*)d_ws;
  float4* perb    = params + Rn;
  bf16*   incb    = (bf16*)(perb + Bn);
  float*  abT     = (float*)(incb + (size_t)Sn * Rn);
  float*  partial = abT + (size_t)(Sn + 1) * Bn;

  prep_all<<<800, 256, 0, stream>>>(inc, incb, alpha, beta, gam, rm, rty,
                                    params, temp, cr, fuv, perb, abund, abT);
  flux_gemm<<<(Bn / BM) * KP, 256, 0, stream>>>(abT, abund, perb, params, incb, partial);
  reduce_k<<<(Bn * Sn) / 1024, 256, 0, stream>>>(partial, out);
}